// Round 5
// baseline (79.877 us; speedup 1.0000x reference)
//
#include <hip/hip_runtime.h>

#define GRID_N 256
#define NBINS  65536   // 256 x-slabs × 256 y-rows

// 8-byte vector load with 4-byte alignment (z-pair may start at odd index).
typedef float float2u __attribute__((ext_vector_type(2), aligned(4)));

// ---------------------------------------------------------------------------
// Per-block 4x4 pose inversion (thread 0 -> LDS). Tiny; avoids extra launch.
// ---------------------------------------------------------------------------
__device__ __forceinline__ void invert_pose_block(const float* __restrict__ pose,
                                                  float* ti) {
    if (threadIdx.x == 0) {
        float a[4][8];
        for (int r = 0; r < 4; ++r)
            for (int c = 0; c < 4; ++c) {
                a[r][c]     = pose[r * 4 + c];
                a[r][c + 4] = (r == c) ? 1.0f : 0.0f;
            }
        for (int c = 0; c < 4; ++c) {
            int piv = c;
            float best = fabsf(a[c][c]);
            for (int r = c + 1; r < 4; ++r) {
                float v = fabsf(a[r][c]);
                if (v > best) { best = v; piv = r; }
            }
            if (piv != c)
                for (int j = 0; j < 8; ++j) {
                    float t = a[c][j]; a[c][j] = a[piv][j]; a[piv][j] = t;
                }
            float inv = 1.0f / a[c][c];
            for (int j = 0; j < 8; ++j) a[c][j] *= inv;
            for (int r = 0; r < 4; ++r) {
                if (r == c) continue;
                float f = a[r][c];
                for (int j = 0; j < 8; ++j) a[r][j] -= f * a[c][j];
            }
        }
        for (int r = 0; r < 3; ++r)
            for (int c = 0; c < 4; ++c)
                ti[r * 4 + c] = a[r][c + 4];
    }
}

// bin key from transformed coords (consistency matters, not exactness)
__device__ __forceinline__ int bin_key(float x, float y,
                                       float x0, float invhx,
                                       float y0, float invhy) {
    int bx = (int)((x - x0) * invhx);
    bx = (bx < 0) ? 0 : ((bx > 255) ? 255 : bx);
    int by = (int)((y - y0) * invhy);
    by = (by < 0) ? 0 : ((by > 255) ? 255 : by);
    return (bx << 8) | by;
}

// ---------------------------------------------------------------------------
// Pass 1: histogram of bin keys.
// ---------------------------------------------------------------------------
__global__ __launch_bounds__(256) void hist_kernel(
    const float* __restrict__ pose, const float* __restrict__ pts,
    const float* __restrict__ xg, const float* __restrict__ yg,
    int* __restrict__ hist, int K) {
    __shared__ float ti[12];
    invert_pose_block(pose, ti);
    __syncthreads();
    const int i = blockIdx.x * blockDim.x + threadIdx.x;
    if (i >= K) return;
    const float px = pts[3 * i], py = pts[3 * i + 1], pz = pts[3 * i + 2];
    const float x = ti[0] * px + ti[1] * py + ti[2] * pz + ti[3];
    const float y = ti[4] * px + ti[5] * py + ti[6] * pz + ti[7];
    const float x0 = xg[0], invhx = 1.0f / (xg[1] - x0);
    const float y0 = yg[0], invhy = 1.0f / (yg[1] - y0);
    atomicAdd(&hist[bin_key(x, y, x0, invhx, y0, invhy)], 1);
}

// ---------------------------------------------------------------------------
// Pass 2: exclusive prefix sum over 65536 bins (single block, 1024 threads,
// 64 bins/thread; Hillis-Steele scan of the 1024 partials in LDS).
// ---------------------------------------------------------------------------
__global__ __launch_bounds__(1024) void prefix_kernel(int* __restrict__ hist) {
    __shared__ int part[1024];
    const int t = threadIdx.x;
    const int base = t * 64;
    int local[64];
    int s = 0;
    for (int j = 0; j < 64; ++j) { local[j] = hist[base + j]; s += local[j]; }
    part[t] = s;
    __syncthreads();
    for (int off = 1; off < 1024; off <<= 1) {
        int v = (t >= off) ? part[t - off] : 0;
        __syncthreads();
        part[t] += v;
        __syncthreads();
    }
    int ex = part[t] - s;  // exclusive prefix of this thread's chunk
    for (int j = 0; j < 64; ++j) { int c = local[j]; hist[base + j] = ex; ex += c; }
}

// ---------------------------------------------------------------------------
// Pass 3: scatter points into sorted order (hist holds running cursors).
// ---------------------------------------------------------------------------
__global__ __launch_bounds__(256) void scatter_kernel(
    const float* __restrict__ pose, const float* __restrict__ pts,
    const float* __restrict__ xg, const float* __restrict__ yg,
    int* __restrict__ hist, float* __restrict__ spts,
    int* __restrict__ sidx, int K) {
    __shared__ float ti[12];
    invert_pose_block(pose, ti);
    __syncthreads();
    const int i = blockIdx.x * blockDim.x + threadIdx.x;
    if (i >= K) return;
    const float px = pts[3 * i], py = pts[3 * i + 1], pz = pts[3 * i + 2];
    const float x = ti[0] * px + ti[1] * py + ti[2] * pz + ti[3];
    const float y = ti[4] * px + ti[5] * py + ti[6] * pz + ti[7];
    const float x0 = xg[0], invhx = 1.0f / (xg[1] - x0);
    const float y0 = yg[0], invhy = 1.0f / (yg[1] - y0);
    const int key = bin_key(x, y, x0, invhx, y0, invhy);
    const int slot = atomicAdd(&hist[key], 1);
    spts[3 * slot + 0] = px;
    spts[3 * slot + 1] = py;
    spts[3 * slot + 2] = pz;
    sidx[slot] = i;
}

// ---------------------------------------------------------------------------
// Pass 4: gather-interpolate in sorted order; 2 points/thread; nontemporal
// 8B z-pair loads; exact searchsorted(side='left') semantics.
// ---------------------------------------------------------------------------
__global__ __launch_bounds__(256) void gather_kernel(
    const float* __restrict__ sdf,
    const float* __restrict__ xg, const float* __restrict__ yg,
    const float* __restrict__ zg, const float* __restrict__ pose,
    const float* __restrict__ spts, const int* __restrict__ sidx,
    float* __restrict__ out, int K) {
    __shared__ float sx[GRID_N];
    __shared__ float sy[GRID_N];
    __shared__ float sz[GRID_N];
    __shared__ float ti[12];
    invert_pose_block(pose, ti);
    sx[threadIdx.x] = xg[threadIdx.x];
    sy[threadIdx.x] = yg[threadIdx.x];
    sz[threadIdx.x] = zg[threadIdx.x];
    __syncthreads();

    const int i0 = blockIdx.x * (blockDim.x * 2) + threadIdx.x;
    const int i1 = i0 + 256;

#define FIND(P, V, L, R)                                                  \
    int L, R;                                                             \
    {                                                                     \
        const float p0 = P[0];                                            \
        const float invh = 1.0f / (P[1] - p0);                            \
        int r = (int)ceilf(((V) - p0) * invh);                            \
        r = (r < 0) ? 0 : ((r > GRID_N - 1) ? GRID_N - 1 : r);            \
        while (r > 0 && P[r - 1] >= (V)) --r;                             \
        while (r < GRID_N - 1 && P[r] < (V)) ++r;                         \
        R = r;                                                            \
        L = (r > 0) ? r - 1 : 0;                                          \
    }

#define WEIGHTS(P, V, IL, IR, DL, DR)                                     \
    float DL = fmaxf((V) - P[IL], 0.0f);                                  \
    float DR = fmaxf(P[IR] - (V), 0.0f);                                  \
    if (DL == 0.0f && DR == 0.0f) { DL = 1.0f; DR = 1.0f; }

    float xA, yA, zA;
    int ixlA, ixrA, iylA, iyrA, izlA, izrA;
    float2u a00, a01, a10, a11;
    if (i0 < K) {
        const float px = spts[3 * i0], py = spts[3 * i0 + 1], pz = spts[3 * i0 + 2];
        xA = ti[0] * px + ti[1] * py + ti[2]  * pz + ti[3];
        yA = ti[4] * px + ti[5] * py + ti[6]  * pz + ti[7];
        zA = ti[8] * px + ti[9] * py + ti[10] * pz + ti[11];
        FIND(sx, xA, l0, r0) ixlA = l0; ixrA = r0;
        FIND(sy, yA, l1, r1) iylA = l1; iyrA = r1;
        FIND(sz, zA, l2, r2) izlA = l2; izrA = r2;
        const int bx0 = ixlA * (GRID_N * GRID_N);
        const int bx1 = ixrA * (GRID_N * GRID_N);
        const int by0 = iylA * GRID_N;
        const int by1 = iyrA * GRID_N;
        a00 = __builtin_nontemporal_load((const float2u*)(sdf + bx0 + by0 + izlA));
        a01 = __builtin_nontemporal_load((const float2u*)(sdf + bx0 + by1 + izlA));
        a10 = __builtin_nontemporal_load((const float2u*)(sdf + bx1 + by0 + izlA));
        a11 = __builtin_nontemporal_load((const float2u*)(sdf + bx1 + by1 + izlA));
    }

    float xB, yB, zB;
    int ixlB, ixrB, iylB, iyrB, izlB, izrB;
    float2u b00, b01, b10, b11;
    if (i1 < K) {
        const float px = spts[3 * i1], py = spts[3 * i1 + 1], pz = spts[3 * i1 + 2];
        xB = ti[0] * px + ti[1] * py + ti[2]  * pz + ti[3];
        yB = ti[4] * px + ti[5] * py + ti[6]  * pz + ti[7];
        zB = ti[8] * px + ti[9] * py + ti[10] * pz + ti[11];
        FIND(sx, xB, l0, r0) ixlB = l0; ixrB = r0;
        FIND(sy, yB, l1, r1) iylB = l1; iyrB = r1;
        FIND(sz, zB, l2, r2) izlB = l2; izrB = r2;
        const int bx0 = ixlB * (GRID_N * GRID_N);
        const int bx1 = ixrB * (GRID_N * GRID_N);
        const int by0 = iylB * GRID_N;
        const int by1 = iyrB * GRID_N;
        b00 = __builtin_nontemporal_load((const float2u*)(sdf + bx0 + by0 + izlB));
        b01 = __builtin_nontemporal_load((const float2u*)(sdf + bx0 + by1 + izlB));
        b10 = __builtin_nontemporal_load((const float2u*)(sdf + bx1 + by0 + izlB));
        b11 = __builtin_nontemporal_load((const float2u*)(sdf + bx1 + by1 + izlB));
    }

    if (i0 < K) {
        WEIGHTS(sx, xA, ixlA, ixrA, dlx, drx)
        WEIGHTS(sy, yA, iylA, iyrA, dly, dry)
        WEIGHTS(sz, zA, izlA, izrA, dlz, drz)
        const bool zs = (izrA == izlA);
        const float v000 = a00.x, v001 = zs ? a00.x : a00.y;
        const float v010 = a01.x, v011 = zs ? a01.x : a01.y;
        const float v100 = a10.x, v101 = zs ? a10.x : a10.y;
        const float v110 = a11.x, v111 = zs ? a11.x : a11.y;
        const float numer =
            drx * (dry * (v000 * drz + v001 * dlz) +
                   dly * (v010 * drz + v011 * dlz)) +
            dlx * (dry * (v100 * drz + v101 * dlz) +
                   dly * (v110 * drz + v111 * dlz));
        const float denom = (dlx + drx) * (dly + dry) * (dlz + drz);
        out[sidx[i0]] = numer / denom;
    }

    if (i1 < K) {
        WEIGHTS(sx, xB, ixlB, ixrB, dlx, drx)
        WEIGHTS(sy, yB, iylB, iyrB, dly, dry)
        WEIGHTS(sz, zB, izlB, izrB, dlz, drz)
        const bool zs = (izrB == izlB);
        const float v000 = b00.x, v001 = zs ? b00.x : b00.y;
        const float v010 = b01.x, v011 = zs ? b01.x : b01.y;
        const float v100 = b10.x, v101 = zs ? b10.x : b10.y;
        const float v110 = b11.x, v111 = zs ? b11.x : b11.y;
        const float numer =
            drx * (dry * (v000 * drz + v001 * dlz) +
                   dly * (v010 * drz + v011 * dlz)) +
            dlx * (dry * (v100 * drz + v101 * dlz) +
                   dly * (v110 * drz + v111 * dlz));
        const float denom = (dlx + drx) * (dly + dry) * (dlz + drz);
        out[sidx[i1]] = numer / denom;
    }
#undef FIND
#undef WEIGHTS
}

// ---------------------------------------------------------------------------
// Fallback: round-4 unsorted kernel (used if ws_size is too small).
// ---------------------------------------------------------------------------
__global__ __launch_bounds__(256) void sdf_interp_unsorted(
    const float* __restrict__ sdf,
    const float* __restrict__ xg, const float* __restrict__ yg,
    const float* __restrict__ zg, const float* __restrict__ pose,
    const float* __restrict__ pts, float* __restrict__ out, int K) {
    __shared__ float sx[GRID_N];
    __shared__ float sy[GRID_N];
    __shared__ float sz[GRID_N];
    __shared__ float ti[12];
    invert_pose_block(pose, ti);
    sx[threadIdx.x] = xg[threadIdx.x];
    sy[threadIdx.x] = yg[threadIdx.x];
    sz[threadIdx.x] = zg[threadIdx.x];
    __syncthreads();
    const int i = blockIdx.x * blockDim.x + threadIdx.x;
    if (i >= K) return;
    const float px = pts[3 * i], py = pts[3 * i + 1], pz = pts[3 * i + 2];
    const float x = ti[0] * px + ti[1] * py + ti[2]  * pz + ti[3];
    const float y = ti[4] * px + ti[5] * py + ti[6]  * pz + ti[7];
    const float z = ti[8] * px + ti[9] * py + ti[10] * pz + ti[11];
#define FIND(P, V, L, R)                                                  \
    int L, R;                                                             \
    {                                                                     \
        const float p0 = P[0];                                            \
        const float invh = 1.0f / (P[1] - p0);                            \
        int r = (int)ceilf(((V) - p0) * invh);                            \
        r = (r < 0) ? 0 : ((r > GRID_N - 1) ? GRID_N - 1 : r);            \
        while (r > 0 && P[r - 1] >= (V)) --r;                             \
        while (r < GRID_N - 1 && P[r] < (V)) ++r;                         \
        R = r;                                                            \
        L = (r > 0) ? r - 1 : 0;                                          \
    }
    FIND(sx, x, ixl, ixr)
    FIND(sy, y, iyl, iyr)
    FIND(sz, z, izl, izr)
#undef FIND
    const int bx0 = ixl * (GRID_N * GRID_N);
    const int bx1 = ixr * (GRID_N * GRID_N);
    const int by0 = iyl * GRID_N;
    const int by1 = iyr * GRID_N;
    const float2u z00 = *(const float2u*)(sdf + bx0 + by0 + izl);
    const float2u z01 = *(const float2u*)(sdf + bx0 + by1 + izl);
    const float2u z10 = *(const float2u*)(sdf + bx1 + by0 + izl);
    const float2u z11 = *(const float2u*)(sdf + bx1 + by1 + izl);
    float dlx = fmaxf(x - sx[ixl], 0.0f);
    float drx = fmaxf(sx[ixr] - x, 0.0f);
    if (dlx == 0.0f && drx == 0.0f) { dlx = 1.0f; drx = 1.0f; }
    float dly = fmaxf(y - sy[iyl], 0.0f);
    float dry = fmaxf(sy[iyr] - y, 0.0f);
    if (dly == 0.0f && dry == 0.0f) { dly = 1.0f; dry = 1.0f; }
    float dlz = fmaxf(z - sz[izl], 0.0f);
    float drz = fmaxf(sz[izr] - z, 0.0f);
    if (dlz == 0.0f && drz == 0.0f) { dlz = 1.0f; drz = 1.0f; }
    const bool zs = (izr == izl);
    const float v000 = z00.x, v001 = zs ? z00.x : z00.y;
    const float v010 = z01.x, v011 = zs ? z01.x : z01.y;
    const float v100 = z10.x, v101 = zs ? z10.x : z10.y;
    const float v110 = z11.x, v111 = zs ? z11.x : z11.y;
    const float numer =
        drx * (dry * (v000 * drz + v001 * dlz) +
               dly * (v010 * drz + v011 * dlz)) +
        dlx * (dry * (v100 * drz + v101 * dlz) +
               dly * (v110 * drz + v111 * dlz));
    const float denom = (dlx + drx) * (dly + dry) * (dlz + drz);
    out[i] = numer / denom;
}

// ---------------------------------------------------------------------------
extern "C" void kernel_launch(void* const* d_in, const int* in_sizes, int n_in,
                              void* d_out, int out_size, void* d_ws, size_t ws_size,
                              hipStream_t stream) {
    const float* sdf  = (const float*)d_in[0];
    const float* xg   = (const float*)d_in[1];
    const float* yg   = (const float*)d_in[2];
    const float* zg   = (const float*)d_in[3];
    const float* pose = (const float*)d_in[4];
    const float* pts  = (const float*)d_in[5];
    float* out = (float*)d_out;

    const int K = in_sizes[5] / 3;
    const size_t need = (size_t)K * 12 + (size_t)K * 4 + (size_t)NBINS * 4;

    if (ws_size < need) {
        const int block = 256;
        const int grid = (K + block - 1) / block;
        sdf_interp_unsorted<<<grid, block, 0, stream>>>(sdf, xg, yg, zg, pose,
                                                        pts, out, K);
        return;
    }

    float* spts = (float*)d_ws;                       // 3*K floats
    int*   sidx = (int*)((char*)d_ws + (size_t)K * 12);  // K ints
    int*   hist = (int*)((char*)d_ws + (size_t)K * 16);  // NBINS ints

    hipMemsetAsync(hist, 0, (size_t)NBINS * 4, stream);

    const int block = 256;
    const int grid1 = (K + block - 1) / block;
    hist_kernel<<<grid1, block, 0, stream>>>(pose, pts, xg, yg, hist, K);
    prefix_kernel<<<1, 1024, 0, stream>>>(hist);
    scatter_kernel<<<grid1, block, 0, stream>>>(pose, pts, xg, yg, hist,
                                                spts, sidx, K);
    const int grid2 = (K + block * 2 - 1) / (block * 2);
    gather_kernel<<<grid2, block, 0, stream>>>(sdf, xg, yg, zg, pose,
                                               spts, sidx, out, K);
}

// Round 6
// 26.535 us; speedup vs baseline: 3.0102x; 3.0102x over previous
//
#include <hip/hip_runtime.h>

#define GRID_N 256

// 8-byte vector load with 4-byte alignment (z-pair may start at odd index).
typedef float float2u __attribute__((ext_vector_type(2), aligned(4)));

// ---------------------------------------------------------------------------
// Per-block 4x4 pose inversion (thread 0 -> LDS). Tiny; avoids extra launch.
// ---------------------------------------------------------------------------
__device__ __forceinline__ void invert_pose_block(const float* __restrict__ pose,
                                                  float* ti) {
    if (threadIdx.x == 0) {
        float a[4][8];
        for (int r = 0; r < 4; ++r)
            for (int c = 0; c < 4; ++c) {
                a[r][c]     = pose[r * 4 + c];
                a[r][c + 4] = (r == c) ? 1.0f : 0.0f;
            }
        for (int c = 0; c < 4; ++c) {
            int piv = c;
            float best = fabsf(a[c][c]);
            for (int r = c + 1; r < 4; ++r) {
                float v = fabsf(a[r][c]);
                if (v > best) { best = v; piv = r; }
            }
            if (piv != c)
                for (int j = 0; j < 8; ++j) {
                    float t = a[c][j]; a[c][j] = a[piv][j]; a[piv][j] = t;
                }
            float inv = 1.0f / a[c][c];
            for (int j = 0; j < 8; ++j) a[c][j] *= inv;
            for (int r = 0; r < 4; ++r) {
                if (r == c) continue;
                float f = a[r][c];
                for (int j = 0; j < 8; ++j) a[r][j] -= f * a[c][j];
            }
        }
        for (int r = 0; r < 3; ++r)
            for (int c = 0; c < 4; ++c)
                ti[r * 4 + c] = a[r][c + 4];
    }
}

// ---------------------------------------------------------------------------
// Single dispatch. 2 points/thread, restructured for maximal early issue:
//   phase 1: BOTH points' pts-loads issue (unconditional, clamped index)
//   phase 2: both transforms + FINDs (VALU, overlaps pts latency tail)
//   phase 3: all 8 sdf gathers issue back-to-back (nontemporal)
//   phase 4: weights + trilinear combine + guarded stores
// ---------------------------------------------------------------------------
__global__ __launch_bounds__(256) void sdf_interp_kernel(
    const float* __restrict__ sdf,
    const float* __restrict__ xg, const float* __restrict__ yg,
    const float* __restrict__ zg, const float* __restrict__ pose,
    const float* __restrict__ pts, float* __restrict__ out, int K) {
    __shared__ float sx[GRID_N];
    __shared__ float sy[GRID_N];
    __shared__ float sz[GRID_N];
    __shared__ float tis[12];
    invert_pose_block(pose, tis);
    sx[threadIdx.x] = xg[threadIdx.x];
    sy[threadIdx.x] = yg[threadIdx.x];
    sz[threadIdx.x] = zg[threadIdx.x];
    __syncthreads();

    const int i0 = blockIdx.x * (blockDim.x * 2) + threadIdx.x;
    const int i1 = i0 + 256;
    const int j0 = (i0 < K) ? i0 : (K - 1);
    const int j1 = (i1 < K) ? i1 : (K - 1);

    // ---- phase 1: issue both pts loads (no exec-mask branch around them)
    const float pxA = pts[3 * j0 + 0];
    const float pyA = pts[3 * j0 + 1];
    const float pzA = pts[3 * j0 + 2];
    const float pxB = pts[3 * j1 + 0];
    const float pyB = pts[3 * j1 + 1];
    const float pzB = pts[3 * j1 + 2];

    // pose rows to registers (uniform LDS broadcast reads)
    const float t0 = tis[0], t1 = tis[1], t2 = tis[2],  t3 = tis[3];
    const float t4 = tis[4], t5 = tis[5], t6 = tis[6],  t7 = tis[7];
    const float t8 = tis[8], t9 = tis[9], t10 = tis[10], t11 = tis[11];

    // ---- phase 2: transforms + FINDs
    const float xA = t0 * pxA + t1 * pyA + t2  * pzA + t3;
    const float yA = t4 * pxA + t5 * pyA + t6  * pzA + t7;
    const float zA = t8 * pxA + t9 * pyA + t10 * pzA + t11;
    const float xB = t0 * pxB + t1 * pyB + t2  * pzB + t3;
    const float yB = t4 * pxB + t5 * pyB + t6  * pzB + t7;
    const float zB = t8 * pxB + t9 * pyB + t10 * pzB + t11;

    // exact lower_bound via affine guess + fixup (monotone grid).
#define FIND(P, V, L, R)                                                  \
    int L, R;                                                             \
    {                                                                     \
        const float p0 = P[0];                                            \
        const float invh = 1.0f / (P[1] - p0);                            \
        int r = (int)ceilf(((V) - p0) * invh);                            \
        r = (r < 0) ? 0 : ((r > GRID_N - 1) ? GRID_N - 1 : r);            \
        while (r > 0 && P[r - 1] >= (V)) --r;                             \
        while (r < GRID_N - 1 && P[r] < (V)) ++r;                         \
        R = r;                                                            \
        L = (r > 0) ? r - 1 : 0;                                          \
    }

    FIND(sx, xA, ixlA, ixrA)
    FIND(sy, yA, iylA, iyrA)
    FIND(sz, zA, izlA, izrA)
    FIND(sx, xB, ixlB, ixrB)
    FIND(sy, yB, iylB, iyrB)
    FIND(sz, zB, izlB, izrB)
#undef FIND

    // ---- phase 3: issue all 8 gathers back-to-back
    const int aBase00 = ixlA * (GRID_N * GRID_N) + iylA * GRID_N + izlA;
    const int aBase01 = ixlA * (GRID_N * GRID_N) + iyrA * GRID_N + izlA;
    const int aBase10 = ixrA * (GRID_N * GRID_N) + iylA * GRID_N + izlA;
    const int aBase11 = ixrA * (GRID_N * GRID_N) + iyrA * GRID_N + izlA;
    const int bBase00 = ixlB * (GRID_N * GRID_N) + iylB * GRID_N + izlB;
    const int bBase01 = ixlB * (GRID_N * GRID_N) + iyrB * GRID_N + izlB;
    const int bBase10 = ixrB * (GRID_N * GRID_N) + iylB * GRID_N + izlB;
    const int bBase11 = ixrB * (GRID_N * GRID_N) + iyrB * GRID_N + izlB;

    const float2u a00 = __builtin_nontemporal_load((const float2u*)(sdf + aBase00));
    const float2u a01 = __builtin_nontemporal_load((const float2u*)(sdf + aBase01));
    const float2u a10 = __builtin_nontemporal_load((const float2u*)(sdf + aBase10));
    const float2u a11 = __builtin_nontemporal_load((const float2u*)(sdf + aBase11));
    const float2u b00 = __builtin_nontemporal_load((const float2u*)(sdf + bBase00));
    const float2u b01 = __builtin_nontemporal_load((const float2u*)(sdf + bBase01));
    const float2u b10 = __builtin_nontemporal_load((const float2u*)(sdf + bBase10));
    const float2u b11 = __builtin_nontemporal_load((const float2u*)(sdf + bBase11));

    // ---- phase 4: weights, combine, stores
#define WEIGHTS(P, V, IL, IR, DL, DR)                                     \
    float DL = fmaxf((V) - P[IL], 0.0f);                                  \
    float DR = fmaxf(P[IR] - (V), 0.0f);                                  \
    if (DL == 0.0f && DR == 0.0f) { DL = 1.0f; DR = 1.0f; }

    {
        WEIGHTS(sx, xA, ixlA, ixrA, dlx, drx)
        WEIGHTS(sy, yA, iylA, iyrA, dly, dry)
        WEIGHTS(sz, zA, izlA, izrA, dlz, drz)
        const bool zs = (izrA == izlA);
        const float v000 = a00.x, v001 = zs ? a00.x : a00.y;
        const float v010 = a01.x, v011 = zs ? a01.x : a01.y;
        const float v100 = a10.x, v101 = zs ? a10.x : a10.y;
        const float v110 = a11.x, v111 = zs ? a11.x : a11.y;
        const float numer =
            drx * (dry * (v000 * drz + v001 * dlz) +
                   dly * (v010 * drz + v011 * dlz)) +
            dlx * (dry * (v100 * drz + v101 * dlz) +
                   dly * (v110 * drz + v111 * dlz));
        const float denom = (dlx + drx) * (dly + dry) * (dlz + drz);
        if (i0 < K) out[i0] = numer / denom;
    }
    {
        WEIGHTS(sx, xB, ixlB, ixrB, dlx, drx)
        WEIGHTS(sy, yB, iylB, iyrB, dly, dry)
        WEIGHTS(sz, zB, izlB, izrB, dlz, drz)
        const bool zs = (izrB == izlB);
        const float v000 = b00.x, v001 = zs ? b00.x : b00.y;
        const float v010 = b01.x, v011 = zs ? b01.x : b01.y;
        const float v100 = b10.x, v101 = zs ? b10.x : b10.y;
        const float v110 = b11.x, v111 = zs ? b11.x : b11.y;
        const float numer =
            drx * (dry * (v000 * drz + v001 * dlz) +
                   dly * (v010 * drz + v011 * dlz)) +
            dlx * (dry * (v100 * drz + v101 * dlz) +
                   dly * (v110 * drz + v111 * dlz));
        const float denom = (dlx + drx) * (dly + dry) * (dlz + drz);
        if (i1 < K) out[i1] = numer / denom;
    }
#undef WEIGHTS
}

// ---------------------------------------------------------------------------
extern "C" void kernel_launch(void* const* d_in, const int* in_sizes, int n_in,
                              void* d_out, int out_size, void* d_ws, size_t ws_size,
                              hipStream_t stream) {
    const float* sdf  = (const float*)d_in[0];
    const float* xg   = (const float*)d_in[1];
    const float* yg   = (const float*)d_in[2];
    const float* zg   = (const float*)d_in[3];
    const float* pose = (const float*)d_in[4];
    const float* pts  = (const float*)d_in[5];
    float* out = (float*)d_out;

    const int K = in_sizes[5] / 3;

    const int block = 256;
    const int grid = (K + block * 2 - 1) / (block * 2);
    sdf_interp_kernel<<<grid, block, 0, stream>>>(sdf, xg, yg, zg, pose, pts,
                                                  out, K);
}

// Round 7
// 25.933 us; speedup vs baseline: 3.0801x; 1.0232x over previous
//
#include <hip/hip_runtime.h>

#define GRID_N 256

// 8-byte vector load with 4-byte alignment (z-pair may start at odd index).
typedef float float2u __attribute__((ext_vector_type(2), aligned(4)));

// ---------------------------------------------------------------------------
// Final kernel (round-4 structure — best measured: 25.6 us).
// Structural ceiling analysis: ~58 MB unique cold 128B lines (poison fills
// sweep L3 between replays), random order, single dispatch. Per-CU L1
// miss-tracking (~32 MSHR x 128B / ~450ns) caps chip gather rate at
// ~2.3 TB/s -> ~25 us. Measured 2.27 TB/s. ILP/TLP/order/locality levers
// all probed (R2-R6); only 2x-ILP + launch fusion moved the needle.
//  - thread 0 of each block inverts the 4x4 pose (Gauss-Jordan) into LDS
//  - all threads stage the coordinate grids into LDS
//  - each thread processes TWO points (overlaps the serial pts-load/FIND
//    phases of the two points; doubles per-wave in-flight lines)
//  - sdf gathers use nontemporal loads (no L1 allocation for lines with
//    negligible hit probability)
// ---------------------------------------------------------------------------
__global__ __launch_bounds__(256) void sdf_interp_kernel(
    const float* __restrict__ sdf,
    const float* __restrict__ xg,
    const float* __restrict__ yg,
    const float* __restrict__ zg,
    const float* __restrict__ pose,
    const float* __restrict__ pts,
    float* __restrict__ out,
    int K) {
    __shared__ float sx[GRID_N];
    __shared__ float sy[GRID_N];
    __shared__ float sz[GRID_N];
    __shared__ float ti[12];

    if (threadIdx.x == 0) {
        // 4x4 Gauss-Jordan inverse (general, matches jnp.linalg.inv semantics)
        float a[4][8];
        for (int r = 0; r < 4; ++r)
            for (int c = 0; c < 4; ++c) {
                a[r][c]     = pose[r * 4 + c];
                a[r][c + 4] = (r == c) ? 1.0f : 0.0f;
            }
        for (int c = 0; c < 4; ++c) {
            int piv = c;
            float best = fabsf(a[c][c]);
            for (int r = c + 1; r < 4; ++r) {
                float v = fabsf(a[r][c]);
                if (v > best) { best = v; piv = r; }
            }
            if (piv != c)
                for (int j = 0; j < 8; ++j) {
                    float t = a[c][j]; a[c][j] = a[piv][j]; a[piv][j] = t;
                }
            float inv = 1.0f / a[c][c];
            for (int j = 0; j < 8; ++j) a[c][j] *= inv;
            for (int r = 0; r < 4; ++r) {
                if (r == c) continue;
                float f = a[r][c];
                for (int j = 0; j < 8; ++j) a[r][j] -= f * a[c][j];
            }
        }
        for (int r = 0; r < 3; ++r)
            for (int c = 0; c < 4; ++c)
                ti[r * 4 + c] = a[r][c + 4];
    }
    sx[threadIdx.x] = xg[threadIdx.x];
    sy[threadIdx.x] = yg[threadIdx.x];
    sz[threadIdx.x] = zg[threadIdx.x];
    __syncthreads();

    const int i0 = blockIdx.x * (blockDim.x * 2) + threadIdx.x;
    const int i1 = i0 + 256;

    // exact lower_bound via affine guess + fixup (monotone grid).
#define FIND(P, V, L, R)                                                  \
    int L, R;                                                             \
    {                                                                     \
        const float p0 = P[0];                                            \
        const float invh = 1.0f / (P[1] - p0);                            \
        int r = (int)ceilf(((V) - p0) * invh);                            \
        r = (r < 0) ? 0 : ((r > GRID_N - 1) ? GRID_N - 1 : r);            \
        while (r > 0 && P[r - 1] >= (V)) --r;                             \
        while (r < GRID_N - 1 && P[r] < (V)) ++r;                         \
        R = r;                                                            \
        L = (r > 0) ? r - 1 : 0;                                          \
    }

#define WEIGHTS(P, V, IL, IR, DL, DR)                                     \
    float DL = fmaxf((V) - P[IL], 0.0f);                                  \
    float DR = fmaxf(P[IR] - (V), 0.0f);                                  \
    if (DL == 0.0f && DR == 0.0f) { DL = 1.0f; DR = 1.0f; }

    // ---- point A ----
    float xA, yA, zA;
    int ixlA, ixrA, iylA, iyrA, izlA, izrA;
    float2u a00, a01, a10, a11;
    if (i0 < K) {
        const float px = pts[3 * i0 + 0];
        const float py = pts[3 * i0 + 1];
        const float pz = pts[3 * i0 + 2];
        xA = ti[0] * px + ti[1] * py + ti[2]  * pz + ti[3];
        yA = ti[4] * px + ti[5] * py + ti[6]  * pz + ti[7];
        zA = ti[8] * px + ti[9] * py + ti[10] * pz + ti[11];
        FIND(sx, xA, l0, r0) ixlA = l0; ixrA = r0;
        FIND(sy, yA, l1, r1) iylA = l1; iyrA = r1;
        FIND(sz, zA, l2, r2) izlA = l2; izrA = r2;
        const int bx0 = ixlA * (GRID_N * GRID_N);
        const int bx1 = ixrA * (GRID_N * GRID_N);
        const int by0 = iylA * GRID_N;
        const int by1 = iyrA * GRID_N;
        a00 = __builtin_nontemporal_load((const float2u*)(sdf + bx0 + by0 + izlA));
        a01 = __builtin_nontemporal_load((const float2u*)(sdf + bx0 + by1 + izlA));
        a10 = __builtin_nontemporal_load((const float2u*)(sdf + bx1 + by0 + izlA));
        a11 = __builtin_nontemporal_load((const float2u*)(sdf + bx1 + by1 + izlA));
    }

    // ---- point B ----
    float xB, yB, zB;
    int ixlB, ixrB, iylB, iyrB, izlB, izrB;
    float2u b00, b01, b10, b11;
    if (i1 < K) {
        const float px = pts[3 * i1 + 0];
        const float py = pts[3 * i1 + 1];
        const float pz = pts[3 * i1 + 2];
        xB = ti[0] * px + ti[1] * py + ti[2]  * pz + ti[3];
        yB = ti[4] * px + ti[5] * py + ti[6]  * pz + ti[7];
        zB = ti[8] * px + ti[9] * py + ti[10] * pz + ti[11];
        FIND(sx, xB, l0, r0) ixlB = l0; ixrB = r0;
        FIND(sy, yB, l1, r1) iylB = l1; iyrB = r1;
        FIND(sz, zB, l2, r2) izlB = l2; izrB = r2;
        const int bx0 = ixlB * (GRID_N * GRID_N);
        const int bx1 = ixrB * (GRID_N * GRID_N);
        const int by0 = iylB * GRID_N;
        const int by1 = iyrB * GRID_N;
        b00 = __builtin_nontemporal_load((const float2u*)(sdf + bx0 + by0 + izlB));
        b01 = __builtin_nontemporal_load((const float2u*)(sdf + bx0 + by1 + izlB));
        b10 = __builtin_nontemporal_load((const float2u*)(sdf + bx1 + by0 + izlB));
        b11 = __builtin_nontemporal_load((const float2u*)(sdf + bx1 + by1 + izlB));
    }

    // ---- finish A ----
    if (i0 < K) {
        WEIGHTS(sx, xA, ixlA, ixrA, dlx, drx)
        WEIGHTS(sy, yA, iylA, iyrA, dly, dry)
        WEIGHTS(sz, zA, izlA, izrA, dlz, drz)
        const bool zs = (izrA == izlA);
        const float v000 = a00.x, v001 = zs ? a00.x : a00.y;
        const float v010 = a01.x, v011 = zs ? a01.x : a01.y;
        const float v100 = a10.x, v101 = zs ? a10.x : a10.y;
        const float v110 = a11.x, v111 = zs ? a11.x : a11.y;
        const float numer =
            drx * (dry * (v000 * drz + v001 * dlz) +
                   dly * (v010 * drz + v011 * dlz)) +
            dlx * (dry * (v100 * drz + v101 * dlz) +
                   dly * (v110 * drz + v111 * dlz));
        const float denom = (dlx + drx) * (dly + dry) * (dlz + drz);
        out[i0] = numer / denom;
    }

    // ---- finish B ----
    if (i1 < K) {
        WEIGHTS(sx, xB, ixlB, ixrB, dlx, drx)
        WEIGHTS(sy, yB, iylB, iyrB, dly, dry)
        WEIGHTS(sz, zB, izlB, izrB, dlz, drz)
        const bool zs = (izrB == izlB);
        const float v000 = b00.x, v001 = zs ? b00.x : b00.y;
        const float v010 = b01.x, v011 = zs ? b01.x : b01.y;
        const float v100 = b10.x, v101 = zs ? b10.x : b10.y;
        const float v110 = b11.x, v111 = zs ? b11.x : b11.y;
        const float numer =
            drx * (dry * (v000 * drz + v001 * dlz) +
                   dly * (v010 * drz + v011 * dlz)) +
            dlx * (dry * (v100 * drz + v101 * dlz) +
                   dly * (v110 * drz + v111 * dlz));
        const float denom = (dlx + drx) * (dly + dry) * (dlz + drz);
        out[i1] = numer / denom;
    }
#undef FIND
#undef WEIGHTS
}

// ---------------------------------------------------------------------------
extern "C" void kernel_launch(void* const* d_in, const int* in_sizes, int n_in,
                              void* d_out, int out_size, void* d_ws, size_t ws_size,
                              hipStream_t stream) {
    const float* sdf  = (const float*)d_in[0];
    const float* xg   = (const float*)d_in[1];
    const float* yg   = (const float*)d_in[2];
    const float* zg   = (const float*)d_in[3];
    const float* pose = (const float*)d_in[4];
    const float* pts  = (const float*)d_in[5];
    float* out = (float*)d_out;

    const int K = in_sizes[5] / 3;

    const int block = 256;
    const int grid = (K + block * 2 - 1) / (block * 2);
    sdf_interp_kernel<<<grid, block, 0, stream>>>(sdf, xg, yg, zg, pose, pts,
                                                  out, K);
}